// Round 2
// baseline (1087.073 us; speedup 1.0000x reference)
//
#include <hip/hip_runtime.h>
#include <math.h>

#define H 64
#define VOCABN 64
#define LSEQ 2048
#define LN_EPS 1e-5f

// ---------- wave-wide all-lane sum (64 lanes): 4 DPP levels within 16, then 2 shuffles ----------
template <int CTRL>
__device__ __forceinline__ float dpp_add(float x) {
  return x + __int_as_float(__builtin_amdgcn_update_dpp(
      0, __float_as_int(x), CTRL, 0xF, 0xF, true));
}
__device__ __forceinline__ float wave_allsum(float x) {
  x = dpp_add<0xB1>(x);   // quad_perm [1,0,3,2]  (xor 1)
  x = dpp_add<0x4E>(x);   // quad_perm [2,3,0,1]  (xor 2)
  x = dpp_add<0x141>(x);  // row_half_mirror      (pairs within 8)
  x = dpp_add<0x140>(x);  // row_mirror           (pairs within 16)
  x += __shfl_xor(x, 16, 64);
  x += __shfl_xor(x, 32, 64);
  return x;
}

// ---------------- Kernel A: per-token tables (encoder collapses to 64 rows) ----------------
__global__ __launch_bounds__(64) void tables_kernel(
    const float* __restrict__ embed, const float* __restrict__ W1, const float* __restrict__ b1,
    const float* __restrict__ W2, const float* __restrict__ b2,
    const float* __restrict__ ln_g, const float* __restrict__ ln_b,
    const float* __restrict__ Wk, const float* __restrict__ Wv,
    float* __restrict__ Htab, float* __restrict__ Ktab, float* __restrict__ Vtab,
    float* __restrict__ nvtab)
{
  __shared__ float hs[H];
  __shared__ float ff1[2 * H];
  __shared__ float lns[H];
  const int c = blockIdx.x;
  const int i = threadIdx.x;

  float e = embed[c * H + i];
  hs[i] = e;
  __syncthreads();

  float r1 = b1[i], r2 = b1[i + H];
  for (int j = 0; j < H; ++j) {
    float hj = hs[j];
    r1 = fmaf(W1[i * H + j], hj, r1);
    r2 = fmaf(W1[(i + H) * H + j], hj, r2);
  }
  ff1[i]     = fmaxf(r1, 0.f);
  ff1[i + H] = fmaxf(r2, 0.f);
  __syncthreads();

  float o = b2[i];
  for (int m = 0; m < 2 * H; ++m) o = fmaf(W2[i * 2 * H + m], ff1[m], o);
  float y = e + o;

  float mu  = wave_allsum(y) * (1.f / H);
  float d   = y - mu;
  float var = wave_allsum(d * d) * (1.f / H);
  float ln  = d * (1.f / sqrtf(var + LN_EPS)) * ln_g[i] + ln_b[i];
  lns[i] = ln;
  __syncthreads();
  Htab[c * H + i] = ln;

  float k = 0.f, v = 0.f;
  for (int j = 0; j < H; ++j) {
    float lj = lns[j];
    k = fmaf(Wk[i * H + j], lj, k);
    v = fmaf(Wv[i * H + j], lj, v);
  }
  float nk = sqrtf(wave_allsum(k * k));
  Ktab[c * H + i] = k / fmaxf(nk, 1e-12f);
  Vtab[c * H + i] = v;
  float nv = sqrtf(wave_allsum(v * v));
  if (i == 0) nvtab[c] = nv;
}

// ---------------- Kernel B: 2048-step delta-rule scan + fused readout ----------------
// One wave per batch element. M rows in registers (lane i = row i).

#define LOADK(KX, VX, NVX, cc) do {                                  \
    const float4* _Kp = (const float4*)(Klds + (cc) * H);            \
    _Pragma("unroll") for (int _q = 0; _q < 16; ++_q) KX[_q] = _Kp[_q]; \
    VX  = Vlds[(cc) * H + lane];                                     \
    NVX = nvlds[cc];                                                 \
  } while (0)

#define STEPC(KX, VX, NVX) do {                                      \
    float _a0 = 0.f, _a1 = 0.f, _a2 = 0.f, _a3 = 0.f;                \
    _Pragma("unroll") for (int _q = 0; _q < 16; ++_q) {              \
      _a0 = fmaf(M[_q].x, KX[_q].x, _a0);                            \
      _a1 = fmaf(M[_q].y, KX[_q].y, _a1);                            \
      _a2 = fmaf(M[_q].z, KX[_q].z, _a2);                            \
      _a3 = fmaf(M[_q].w, KX[_q].w, _a3);                            \
    }                                                                \
    float _pred  = (_a0 + _a1) + (_a2 + _a3);                        \
    float _delta = VX - _pred;                                       \
    float _nd2   = wave_allsum(_delta * _delta);                     \
    float _nds = __int_as_float(__builtin_amdgcn_readfirstlane(      \
                     __float_as_int(sqrtf(_nd2))));                  \
    float _nvs = __int_as_float(__builtin_amdgcn_readfirstlane(      \
                     __float_as_int(NVX)));                          \
    if (_nds > 0.4f * _nvs) {                                        \
      _Pragma("unroll") for (int _q = 0; _q < 16; ++_q) {            \
        M[_q].x = fmaf(_delta, KX[_q].x, M[_q].x);                   \
        M[_q].y = fmaf(_delta, KX[_q].y, M[_q].y);                   \
        M[_q].z = fmaf(_delta, KX[_q].z, M[_q].z);                   \
        M[_q].w = fmaf(_delta, KX[_q].w, M[_q].w);                   \
      }                                                              \
    }                                                                \
  } while (0)

__global__ __launch_bounds__(64, 1) void scan_kernel(
    const int* __restrict__ x, const float* __restrict__ Htab,
    const float* __restrict__ Ktab, const float* __restrict__ Vtab,
    const float* __restrict__ nvtab,
    const float* __restrict__ Wq, const float* __restrict__ Wr,
    const float* __restrict__ alpha, const float* __restrict__ Wout,
    const float* __restrict__ bout, float* __restrict__ out)
{
  __shared__ float4 Klds4[VOCABN * H / 4];
  __shared__ float4 Vlds4[VOCABN * H / 4];
  __shared__ int4   xlds4[LSEQ / 4];
  __shared__ float  nvlds[VOCABN];
  __shared__ float  hbuf[H];
  __shared__ float  qbuf[H];
  __shared__ float  mbuf[H];
  float* Klds = (float*)Klds4;
  float* Vlds = (float*)Vlds4;
  int*   xlds = (int*)xlds4;

  const int b = blockIdx.x;
  const int lane = threadIdx.x;

  // ---- stage tables + token row into LDS ----
  {
    const float4* Kg = (const float4*)Ktab;
    const float4* Vg = (const float4*)Vtab;
    for (int q = lane; q < VOCABN * H / 4; q += 64) { Klds4[q] = Kg[q]; Vlds4[q] = Vg[q]; }
    const int4* xg = (const int4*)(x + b * LSEQ);
    for (int q = lane; q < LSEQ / 4; q += 64) xlds4[q] = xg[q];
    nvlds[lane] = nvtab[lane];
  }
  __syncthreads();

  float4 M[16];
#pragma unroll
  for (int q = 0; q < 16; ++q) M[q] = make_float4(0.f, 0.f, 0.f, 0.f);

  float4 kA[16], kB[16];
  float vA, vB, nvA, nvB;

  int c0 = xlds[0];
  LOADK(kA, vA, nvA, c0);
  int c1 = xlds[1];

  for (int t = 0; t < LSEQ; t += 2) {
    LOADK(kB, vB, nvB, c1);
    int c2 = (t + 2 < LSEQ) ? xlds[t + 2] : 0;
    STEPC(kA, vA, nvA);
    LOADK(kA, vA, nvA, c2);
    c1 = (t + 3 < LSEQ) ? xlds[t + 3] : 0;
    STEPC(kB, vB, nvB);
  }

  // ---------------- fused readout ----------------
  __syncthreads();
  // M row-major into Klds (M_N[i*H+j]), transposed into Vlds (M_T[j*H+i])
  {
    float4* MN = (float4*)(Klds + lane * H);
#pragma unroll
    for (int q = 0; q < 16; ++q) MN[q] = M[q];
#pragma unroll
    for (int q = 0; q < 16; ++q) {
      Vlds[(4 * q + 0) * H + lane] = M[q].x;
      Vlds[(4 * q + 1) * H + lane] = M[q].y;
      Vlds[(4 * q + 2) * H + lane] = M[q].z;
      Vlds[(4 * q + 3) * H + lane] = M[q].w;
    }
  }
  __syncthreads();

  const int clast = xlds[LSEQ - 1];
  hbuf[lane] = Htab[clast * H + lane];
  __syncthreads();

  float qi = 0.f;
  for (int j = 0; j < H; ++j) qi = fmaf(Wq[lane * H + j], hbuf[j], qi);
  qbuf[lane] = qi;
  __syncthreads();

  float qri = 0.f;
  for (int j = 0; j < H; ++j) qri = fmaf(Wr[lane * H + j], qbuf[j], qri);

  // slot norms^2: slot s = column s of M; lane s reads M_N[i*H+s] (conflict-free)
  float n2 = 0.f;
  for (int i2 = 0; i2 < H; ++i2) { float m = Klds[i2 * H + lane]; n2 = fmaf(m, m, n2); }

  // top-8 slots by norm (ties -> smaller index, matching lax.top_k)
  const int KS = 8;
  int idxs[KS];
  float nloc = n2;
#pragma unroll
  for (int k = 0; k < KS; ++k) {
    float v = nloc; int idx = lane;
#pragma unroll
    for (int s = 1; s < 64; s <<= 1) {
      float ov = __shfl_xor(v, s, 64);
      int   oi = __shfl_xor(idx, s, 64);
      if (ov > v || (ov == v && oi < idx)) { v = ov; idx = oi; }
    }
    idxs[k] = idx;
    if (lane == idx) nloc = -1.f;
  }

  // logits + selected slot values (sel[k][lane] = M_T[idx_k*H + lane])
  float sel[KS], lg[KS];
#pragma unroll
  for (int k = 0; k < KS; ++k) {
    float s = Vlds[idxs[k] * H + lane];
    sel[k] = s;
    lg[k] = wave_allsum(s * qri) * 0.125f;   // / sqrt(64)
  }
  float lmax = lg[0];
#pragma unroll
  for (int k = 1; k < KS; ++k) lmax = fmaxf(lmax, lg[k]);
  float esum = 0.f, retro = 0.f;
#pragma unroll
  for (int k = 0; k < KS; ++k) {
    float e = expf(lg[k] - lmax);
    esum += e;
    retro = fmaf(e, sel[k], retro);
  }
  retro /= esum;

  // m_ctx = M q  (M rows still in registers; q broadcast from LDS)
  float mc = 0.f;
#pragma unroll
  for (int q2 = 0; q2 < 16; ++q2) {
    mc = fmaf(M[q2].x, qbuf[4 * q2 + 0], mc);
    mc = fmaf(M[q2].y, qbuf[4 * q2 + 1], mc);
    mc = fmaf(M[q2].z, qbuf[4 * q2 + 2], mc);
    mc = fmaf(M[q2].w, qbuf[4 * q2 + 3], mc);
  }

  float a = 1.f / (1.f + expf(-alpha[0]));
  float mixed = fmaxf(fmaf(a, retro, (1.f - a) * mc), 0.f);
  mbuf[lane] = mixed;
  __syncthreads();

  float oo = bout[lane];
  for (int i2 = 0; i2 < H; ++i2) oo = fmaf(Wout[lane * H + i2], mbuf[i2], oo);
  out[b * VOCABN + lane] = oo;
}

extern "C" void kernel_launch(void* const* d_in, const int* in_sizes, int n_in,
                              void* d_out, int out_size, void* d_ws, size_t ws_size,
                              hipStream_t stream) {
  const int*   x     = (const int*)d_in[0];
  const float* embed = (const float*)d_in[1];
  const float* W1    = (const float*)d_in[2];
  const float* b1    = (const float*)d_in[3];
  const float* W2    = (const float*)d_in[4];
  const float* b2    = (const float*)d_in[5];
  const float* ln_g  = (const float*)d_in[6];
  const float* ln_b  = (const float*)d_in[7];
  const float* Wk    = (const float*)d_in[8];
  const float* Wv    = (const float*)d_in[9];
  const float* Wq    = (const float*)d_in[10];
  const float* Wr    = (const float*)d_in[11];
  const float* alpha = (const float*)d_in[12];
  const float* Wout  = (const float*)d_in[13];
  const float* bout  = (const float*)d_in[14];
  float* out = (float*)d_out;

  const int B = in_sizes[0] / LSEQ;

  float* ws    = (float*)d_ws;
  float* Htab  = ws;          // 4096
  float* Ktab  = ws + 4096;   // 4096
  float* Vtab  = ws + 8192;   // 4096
  float* nvtab = ws + 12288;  // 64

  tables_kernel<<<VOCABN, 64, 0, stream>>>(embed, W1, b1, W2, b2, ln_g, ln_b,
                                           Wk, Wv, Htab, Ktab, Vtab, nvtab);
  scan_kernel<<<B, 64, 0, stream>>>(x, Htab, Ktab, Vtab, nvtab,
                                    Wq, Wr, alpha, Wout, bout, out);
}

// Round 3
// 981.381 us; speedup vs baseline: 1.1077x; 1.1077x over previous
//
#include <hip/hip_runtime.h>
#include <math.h>

#define H 64
#define VOCABN 64
#define LSEQ 2048
#define LN_EPS 1e-5f

// ---------- generic DPP add helper ----------
template <int CTRL>
__device__ __forceinline__ float dpp_add(float x) {
  return x + __int_as_float(__builtin_amdgcn_update_dpp(
      0, __float_as_int(x), CTRL, 0xF, 0xF, true));
}

// all-lane sum with broadcast result (readout / tables only; uses 2 LDS-unit shuffles)
__device__ __forceinline__ float wave_allsum(float x) {
  x = dpp_add<0xB1>(x);   // quad_perm [1,0,3,2]
  x = dpp_add<0x4E>(x);   // quad_perm [2,3,0,1]
  x = dpp_add<0x141>(x);  // row_half_mirror
  x = dpp_add<0x140>(x);  // row_mirror
  x += __shfl_xor(x, 16, 64);
  x += __shfl_xor(x, 32, 64);
  return x;
}

// all-VALU wave64 reduction: total lands in lane 63 (row_shr + row_bcast chain)
__device__ __forceinline__ float reduce_to_lane63(float x) {
  x = dpp_add<0x111>(x);  // row_shr:1
  x = dpp_add<0x112>(x);  // row_shr:2
  x = dpp_add<0x114>(x);  // row_shr:4
  x = dpp_add<0x118>(x);  // row_shr:8  -> lanes 15/31/47/63 hold row sums
  x = dpp_add<0x142>(x);  // row_bcast:15 -> lane 31 = rows0+1, lane 63 = rows2+3
  x = dpp_add<0x143>(x);  // row_bcast:31 -> lane 63 = total
  return x;
}

// ---------------- Kernel A: per-token tables (encoder collapses to 64 rows) ----------------
__global__ __launch_bounds__(64) void tables_kernel(
    const float* __restrict__ embed, const float* __restrict__ W1, const float* __restrict__ b1,
    const float* __restrict__ W2, const float* __restrict__ b2,
    const float* __restrict__ ln_g, const float* __restrict__ ln_b,
    const float* __restrict__ Wk, const float* __restrict__ Wv,
    float* __restrict__ Htab, float* __restrict__ Ktab, float* __restrict__ Vtab,
    float* __restrict__ nvtab)
{
  __shared__ float hs[H];
  __shared__ float ff1[2 * H];
  __shared__ float lns[H];
  const int c = blockIdx.x;
  const int i = threadIdx.x;

  float e = embed[c * H + i];
  hs[i] = e;
  __syncthreads();

  float r1 = b1[i], r2 = b1[i + H];
  for (int j = 0; j < H; ++j) {
    float hj = hs[j];
    r1 = fmaf(W1[i * H + j], hj, r1);
    r2 = fmaf(W1[(i + H) * H + j], hj, r2);
  }
  ff1[i]     = fmaxf(r1, 0.f);
  ff1[i + H] = fmaxf(r2, 0.f);
  __syncthreads();

  float o = b2[i];
  for (int m = 0; m < 2 * H; ++m) o = fmaf(W2[i * 2 * H + m], ff1[m], o);
  float y = e + o;

  float mu  = wave_allsum(y) * (1.f / H);
  float d   = y - mu;
  float var = wave_allsum(d * d) * (1.f / H);
  float ln  = d * (1.f / sqrtf(var + LN_EPS)) * ln_g[i] + ln_b[i];
  lns[i] = ln;
  __syncthreads();
  Htab[c * H + i] = ln;

  float k = 0.f, v = 0.f;
  for (int j = 0; j < H; ++j) {
    float lj = lns[j];
    k = fmaf(Wk[i * H + j], lj, k);
    v = fmaf(Wv[i * H + j], lj, v);
  }
  float nk = sqrtf(wave_allsum(k * k));
  Ktab[c * H + i] = k / fmaxf(nk, 1e-12f);
  Vtab[c * H + i] = v;
  float nv = sqrtf(wave_allsum(v * v));
  if (i == 0) nvtab[c] = 0.4f * nv;   // pre-scaled gate threshold
}

// ---------------- Kernel B: 2048-step delta-rule scan + fused readout ----------------
// One wave per batch element. M rows in registers (lane i = row i).

#define LOADK(KX, VX, NVX, cc) do {                                  \
    const float4* _Kp = (const float4*)(Klds + (cc) * H);            \
    _Pragma("unroll") for (int _q = 0; _q < 16; ++_q) KX[_q] = _Kp[_q]; \
    VX  = Vlds[(cc) * H + lane];                                     \
    NVX = nvlds[cc];                                                 \
  } while (0)

#define STEPC(KX, VX, NVX) do {                                      \
    float _a0 = 0.f, _a1 = 0.f, _a2 = 0.f, _a3 = 0.f;                \
    _Pragma("unroll") for (int _q = 0; _q < 16; ++_q) {              \
      _a0 = fmaf(M[_q].x, KX[_q].x, _a0);                            \
      _a1 = fmaf(M[_q].y, KX[_q].y, _a1);                            \
      _a2 = fmaf(M[_q].z, KX[_q].z, _a2);                            \
      _a3 = fmaf(M[_q].w, KX[_q].w, _a3);                            \
    }                                                                \
    float _pred  = (_a0 + _a1) + (_a2 + _a3);                        \
    float _delta = VX - _pred;                                       \
    float _nd2   = reduce_to_lane63(_delta * _delta);                \
    float _nds = __int_as_float(__builtin_amdgcn_readlane(           \
                     __float_as_int(sqrtf(_nd2)), 63));              \
    float _thr = __int_as_float(__builtin_amdgcn_readfirstlane(      \
                     __float_as_int(NVX)));                          \
    if (_nds > _thr) {                                               \
      _Pragma("unroll") for (int _q = 0; _q < 16; ++_q) {            \
        M[_q].x = fmaf(_delta, KX[_q].x, M[_q].x);                   \
        M[_q].y = fmaf(_delta, KX[_q].y, M[_q].y);                   \
        M[_q].z = fmaf(_delta, KX[_q].z, M[_q].z);                   \
        M[_q].w = fmaf(_delta, KX[_q].w, M[_q].w);                   \
      }                                                              \
    }                                                                \
  } while (0)

__global__ __launch_bounds__(64, 1) void scan_kernel(
    const int* __restrict__ x, const float* __restrict__ Htab,
    const float* __restrict__ Ktab, const float* __restrict__ Vtab,
    const float* __restrict__ nvtab,
    const float* __restrict__ Wq, const float* __restrict__ Wr,
    const float* __restrict__ alpha, const float* __restrict__ Wout,
    const float* __restrict__ bout, float* __restrict__ out)
{
  __shared__ float4 Klds4[VOCABN * H / 4];
  __shared__ float4 Vlds4[VOCABN * H / 4];
  __shared__ int4   xlds4[LSEQ / 4];
  __shared__ float  nvlds[VOCABN];
  __shared__ float  hbuf[H];
  __shared__ float  qbuf[H];
  __shared__ float  mbuf[H];
  float* Klds = (float*)Klds4;
  float* Vlds = (float*)Vlds4;
  int*   xlds = (int*)xlds4;

  const int b = blockIdx.x;
  const int lane = threadIdx.x;

  // ---- stage tables + token row into LDS ----
  {
    const float4* Kg = (const float4*)Ktab;
    const float4* Vg = (const float4*)Vtab;
    for (int q = lane; q < VOCABN * H / 4; q += 64) { Klds4[q] = Kg[q]; Vlds4[q] = Vg[q]; }
    const int4* xg = (const int4*)(x + b * LSEQ);
    for (int q = lane; q < LSEQ / 4; q += 64) xlds4[q] = xg[q];
    nvlds[lane] = nvtab[lane];
  }
  __syncthreads();

  float4 M[16];
#pragma unroll
  for (int q = 0; q < 16; ++q) M[q] = make_float4(0.f, 0.f, 0.f, 0.f);

  float4 kA[16], kB[16];
  float vA, vB, nvA, nvB;

  int c0 = xlds[0];
  LOADK(kA, vA, nvA, c0);
  int c1 = xlds[1];

  for (int t = 0; t < LSEQ; t += 2) {
    LOADK(kB, vB, nvB, c1);
    int c2 = (t + 2 < LSEQ) ? xlds[t + 2] : 0;
    STEPC(kA, vA, nvA);
    LOADK(kA, vA, nvA, c2);
    c1 = (t + 3 < LSEQ) ? xlds[t + 3] : 0;
    STEPC(kB, vB, nvB);
  }

  // ---------------- fused readout ----------------
  __syncthreads();
  // M row-major into Klds (M_N[i*H+j]), transposed into Vlds (M_T[j*H+i])
  {
    float4* MN = (float4*)(Klds + lane * H);
#pragma unroll
    for (int q = 0; q < 16; ++q) MN[q] = M[q];
#pragma unroll
    for (int q = 0; q < 16; ++q) {
      Vlds[(4 * q + 0) * H + lane] = M[q].x;
      Vlds[(4 * q + 1) * H + lane] = M[q].y;
      Vlds[(4 * q + 2) * H + lane] = M[q].z;
      Vlds[(4 * q + 3) * H + lane] = M[q].w;
    }
  }
  __syncthreads();

  const int clast = xlds[LSEQ - 1];
  hbuf[lane] = Htab[clast * H + lane];
  __syncthreads();

  float qi = 0.f;
  for (int j = 0; j < H; ++j) qi = fmaf(Wq[lane * H + j], hbuf[j], qi);
  qbuf[lane] = qi;
  __syncthreads();

  float qri = 0.f;
  for (int j = 0; j < H; ++j) qri = fmaf(Wr[lane * H + j], qbuf[j], qri);

  // slot norms^2: slot s = column s of M; lane s reads M_N[i*H+s] (conflict-free)
  float n2 = 0.f;
  for (int i2 = 0; i2 < H; ++i2) { float m = Klds[i2 * H + lane]; n2 = fmaf(m, m, n2); }

  // top-8 slots by norm (ties -> smaller index, matching lax.top_k)
  const int KS = 8;
  int idxs[KS];
  float nloc = n2;
#pragma unroll
  for (int k = 0; k < KS; ++k) {
    float v = nloc; int idx = lane;
#pragma unroll
    for (int s = 1; s < 64; s <<= 1) {
      float ov = __shfl_xor(v, s, 64);
      int   oi = __shfl_xor(idx, s, 64);
      if (ov > v || (ov == v && oi < idx)) { v = ov; idx = oi; }
    }
    idxs[k] = idx;
    if (lane == idx) nloc = -1.f;
  }

  // logits + selected slot values (sel[k][lane] = M_T[idx_k*H + lane])
  float sel[KS], lg[KS];
#pragma unroll
  for (int k = 0; k < KS; ++k) {
    float s = Vlds[idxs[k] * H + lane];
    sel[k] = s;
    lg[k] = wave_allsum(s * qri) * 0.125f;   // / sqrt(64)
  }
  float lmax = lg[0];
#pragma unroll
  for (int k = 1; k < KS; ++k) lmax = fmaxf(lmax, lg[k]);
  float esum = 0.f, retro = 0.f;
#pragma unroll
  for (int k = 0; k < KS; ++k) {
    float e = expf(lg[k] - lmax);
    esum += e;
    retro = fmaf(e, sel[k], retro);
  }
  retro /= esum;

  // m_ctx = M q  (M rows still in registers; q broadcast from LDS)
  float mc = 0.f;
#pragma unroll
  for (int q2 = 0; q2 < 16; ++q2) {
    mc = fmaf(M[q2].x, qbuf[4 * q2 + 0], mc);
    mc = fmaf(M[q2].y, qbuf[4 * q2 + 1], mc);
    mc = fmaf(M[q2].z, qbuf[4 * q2 + 2], mc);
    mc = fmaf(M[q2].w, qbuf[4 * q2 + 3], mc);
  }

  float a = 1.f / (1.f + expf(-alpha[0]));
  float mixed = fmaxf(fmaf(a, retro, (1.f - a) * mc), 0.f);
  mbuf[lane] = mixed;
  __syncthreads();

  float oo = bout[lane];
  for (int i2 = 0; i2 < H; ++i2) oo = fmaf(Wout[lane * H + i2], mbuf[i2], oo);
  out[b * VOCABN + lane] = oo;
}

extern "C" void kernel_launch(void* const* d_in, const int* in_sizes, int n_in,
                              void* d_out, int out_size, void* d_ws, size_t ws_size,
                              hipStream_t stream) {
  const int*   x     = (const int*)d_in[0];
  const float* embed = (const float*)d_in[1];
  const float* W1    = (const float*)d_in[2];
  const float* b1    = (const float*)d_in[3];
  const float* W2    = (const float*)d_in[4];
  const float* b2    = (const float*)d_in[5];
  const float* ln_g  = (const float*)d_in[6];
  const float* ln_b  = (const float*)d_in[7];
  const float* Wk    = (const float*)d_in[8];
  const float* Wv    = (const float*)d_in[9];
  const float* Wq    = (const float*)d_in[10];
  const float* Wr    = (const float*)d_in[11];
  const float* alpha = (const float*)d_in[12];
  const float* Wout  = (const float*)d_in[13];
  const float* bout  = (const float*)d_in[14];
  float* out = (float*)d_out;

  const int B = in_sizes[0] / LSEQ;

  float* ws    = (float*)d_ws;
  float* Htab  = ws;          // 4096
  float* Ktab  = ws + 4096;   // 4096
  float* Vtab  = ws + 8192;   // 4096
  float* nvtab = ws + 12288;  // 64

  tables_kernel<<<VOCABN, 64, 0, stream>>>(embed, W1, b1, W2, b2, ln_g, ln_b,
                                           Wk, Wv, Htab, Ktab, Vtab, nvtab);
  scan_kernel<<<B, 64, 0, stream>>>(x, Htab, Ktab, Vtab, nvtab,
                                    Wq, Wr, alpha, Wout, bout, out);
}